// Round 8
// baseline (712.559 us; speedup 1.0000x reference)
//
#include <hip/hip_runtime.h>
#include <hip/hip_bf16.h>

typedef __hip_bfloat16 bf16;
typedef float v2f __attribute__((ext_vector_type(2)));

#define LEN 1024
#define N2 2048            // B * L rows
#define SCALE_L2E 0.5100697918f   // (1/sqrt(8)) * log2(e)

// ---- converted-input float offsets in ws ----
#define I_SCTX   0
#define I_FCTX   4096
#define I_STEST  6144
#define I_OBS    10240
#define I_EW1    10248
#define I_EB1    12040
#define I_EW2    12296
#define I_EB2    28680
#define I_WQ     28744
#define I_BQ     53320
#define I_WK     53704
#define I_BK     78280
#define I_WV     78664
#define I_BV     103240
#define I_WO     103624
#define I_BO     128200
#define I_FW1    128584
#define I_FB1    177736
#define I_FW2    178504
#define I_FB2    227656
#define I_BW1    228040
#define I_BB1    228136
#define I_BW2    228232
#define I_BB2    229000
#define I_NS     229048
#define I_NB     229432
#define I_FNS    229816
#define I_FNB    229880
#define I_HW1    229944
#define I_HB1    238136
#define I_HW2    238264
#define I_HB2    238520

#define OFF_PW   240256    // 6 layers x 288 floats
#define OFF_QVS  262144
#define OFF_KVS  393216
#define OFF_Q1   524288
#define OFF_Q2   655360
#define OFF_KB   786432
#define OFF_VB   917504
#define OFF_PART 1048576   // partials: [z=4][row=1024][h=8][ks=8][6] floats, h-major interleave

__constant__ int C_OFFS[33] = {
    0, 4096, 6144, 10240, 10248, 12040, 12296, 28680, 28744, 53320, 53704,
    78280, 78664, 103240, 103624, 128200, 128584, 177736, 178504, 227656,
    228040, 228136, 228232, 229000, 229048, 229432, 229816, 229880, 229944,
    238136, 238264, 238520, 238522 };

struct InPtrs { const void* p[32]; };

__device__ __forceinline__ float pack2(float a, float b) {
    __hip_bfloat16 ha = __float2bfloat16(a), hb = __float2bfloat16(b);
    unsigned ua = *(unsigned short*)&ha, ub = *(unsigned short*)&hb;
    return __uint_as_float(ua | (ub << 16));
}
__device__ __forceinline__ float unlo(float f) {
    return __uint_as_float(__float_as_uint(f) << 16);
}
__device__ __forceinline__ float unhi(float f) {
    return __uint_as_float(__float_as_uint(f) & 0xffff0000u);
}

// ---------------- convert all inputs to f32 in ws ----------------
__global__ __launch_bounds__(256) void k_cvt(InPtrs ptrs, float* ws) {
    const unsigned u0 = *(const unsigned*)ptrs.p[24];   // norm_scale = ones
    const int isbf = (u0 == 0x3F803F80u);
    const int i = blockIdx.y;
    const int o0 = C_OFFS[i], n = C_OFFS[i + 1] - o0;
    const void* src = ptrs.p[i];
    for (int j = blockIdx.x * 256 + threadIdx.x; j < n; j += gridDim.x * 256) {
        float v = isbf ? __bfloat162float(((const bf16*)src)[j])
                       : ((const float*)src)[j];
        ws[o0 + j] = v;
    }
}

// ---- piecewise-linear form of the distance-bias MLP, per layer ----
__global__ __launch_bounds__(256) void k_pw(float* ws) {
    const int L = blockIdx.x, t = threadIdx.x;
    __shared__ float w1s[16], b1s[16], bps[16];
    __shared__ int rnk[16];
    if (t < 16) {
        float w = ws[I_BW1 + L * 16 + t], b0 = ws[I_BB1 + L * 16 + t];
        w1s[t] = w; b1s[t] = b0;
        bps[t] = (w != 0.f) ? (-b0 / w) : 1e30f;
    }
    __syncthreads();
    if (t < 16) {
        float me = bps[t]; int r = 0;
        for (int j = 0; j < 16; ++j) {
            float o = bps[j];
            if (o < me || (o == me && j < t)) ++r;
        }
        rnk[t] = r;
    }
    __syncthreads();
    if (t < 16) ws[OFF_PW + L * 288 + 272 + rnk[t]] = bps[t];
    if (t < 136) {
        int s = t >> 3, h = t & 7;
        float slope = 0.f, inter = ws[I_BB2 + L * 8 + h];
        for (int j = 0; j < 16; ++j) {
            float w = w1s[j];
            bool act = (w > 0.f) ? (rnk[j] < s)
                     : (w < 0.f) ? (rnk[j] >= s)
                                 : (b1s[j] > 0.f);
            if (act) {
                float w2v = ws[I_BW2 + L * 128 + j * 8 + h];
                slope += w * w2v;
                inter += b1s[j] * w2v;
            }
        }
        const float LOG2E = 1.4426950408889634f;
        ws[OFF_PW + L * 288 + (s * 8 + h) * 2]     = slope * LOG2E;
        ws[OFF_PW + L * 288 + (s * 8 + h) * 2 + 1] = inter * LOG2E;
    }
}

// ---------------- embed MLP: 7 -> 256 relu -> 64 ----------------
__global__ __launch_bounds__(256) void k_embed(float* ws) {
    __shared__ float hbuf[256];
    __shared__ float red[256];
    int r = blockIdx.x, t = threadIdx.x;
    bool is_ctx = (r < N2);
    int rr = is_ctx ? r : r - N2;
    const float* ob = ws + I_OBS + (is_ctx ? 4 : 0);
    const float* s  = ws + (is_ctx ? I_SCTX : I_STEST);
    float in[7];
    in[0] = ob[0]; in[1] = ob[1]; in[2] = ob[2]; in[3] = ob[3];
    in[4] = s[rr * 2]; in[5] = s[rr * 2 + 1];
    in[6] = is_ctx ? ws[I_FCTX + rr] : 0.f;

    float acc = ws[I_EB1 + t];
#pragma unroll
    for (int i = 0; i < 7; ++i) acc += in[i] * ws[I_EW1 + i * 256 + t];
    hbuf[t] = fmaxf(acc, 0.f);
    __syncthreads();

    int d = t & 63, p = t >> 6;
    float a2 = 0.f;
#pragma unroll 8
    for (int j = p * 64; j < p * 64 + 64; ++j) a2 += hbuf[j] * ws[I_EW2 + j * 64 + d];
    red[t] = a2;
    __syncthreads();
    if (t < 64) {
        float o = red[t] + red[64 + t] + red[128 + t] + red[192 + t] + ws[I_EB2 + t];
        float* dst = ws + (is_ctx ? OFF_KVS : OFF_QVS);
        dst[rr * 64 + t] = o;
    }
}

// ---------------- QKV projections (layer 0 only) ----------------
__global__ __launch_bounds__(256) void k_qkv(int blk, float* ws) {
    __shared__ float xs[2][64];
    int r = blockIdx.x, t = threadIdx.x;
    if (t < 64)       xs[0][t] = ws[OFF_QVS + r * 64 + t];
    else if (t < 128) xs[1][t - 64] = ws[OFF_KVS + r * 64 + (t - 64)];
    __syncthreads();
    int o = t >> 6, d = t & 63;
    const float* x = (o == 0) ? xs[0] : xs[1];
    const float* W; const float* bb; float* dst;
    if (o <= 1)      { W = ws + I_WQ + blk * 4096; bb = ws + I_BQ + blk * 64; dst = ws + (o == 0 ? OFF_Q1 : OFF_Q2); }
    else if (o == 2) { W = ws + I_WK + blk * 4096; bb = ws + I_BK + blk * 64; dst = ws + OFF_KB; }
    else             { W = ws + I_WV + blk * 4096; bb = ws + I_BV + blk * 64; dst = ws + OFF_VB; }
    float acc = bb[d];
#pragma unroll 8
    for (int k = 0; k < 64; ++k) acc += x[k] * W[k * 64 + d];
    dst[r * 64 + d] = acc;
}

// ---- attention, K-split 8, 2 q-rows/thread, interleaved bf16 partials ----
// grid (qt=64, ks=8, z=4), z = kind*2 + b. Block covers K-tiles [ks*4, ks*4+4).
// thread = (q2 = t>>5 in [0,8), h2 = (t>>2)&7, par = t&3); keys k = par + 4j.
__global__ __launch_bounds__(256, 7) void k_attn(int blk, float* ws) {
    __shared__ float Ks[2176];     // 32 x 68
    __shared__ float Vs[2176];
    __shared__ float Sds[544];     // [k*17+q]: d with seg packed in low 5 mantissa bits
    __shared__ v2f   pw[136];

    const int t = threadIdx.x;
    const int qt = blockIdx.x, ks = blockIdx.y, z = blockIdx.z;
    const int b = z & 1, kind = z >> 1;
    const int q0 = qt * 16;
    const float* Qbuf = ws + (kind == 0 ? OFF_Q1 : OFF_Q2);
    const float* Kbuf = ws + OFF_KB;
    const float* Vbuf = ws + OFF_VB;
    const float* sq_src = ws + (kind == 0 ? I_STEST : I_SCTX);
    const float* sk_src = ws + I_SCTX;
    const float* pwg = ws + OFF_PW + blk * 288;   // uniform -> scalar loads

    float bp[16];
#pragma unroll
    for (int j = 0; j < 16; ++j) bp[j] = pwg[272 + j];

    if (t < 136) pw[t] = (v2f){ pwg[t * 2], pwg[t * 2 + 1] };

    const int q2 = t >> 5, h2 = (t >> 2) & 7, par = t & 3;
    // Sds precompute mapping (independent)
    const int pq = t >> 4, pk = t & 15;
    float sqx, sqy;
    {
        const float* sp = sq_src + (b * LEN + q0 + pq) * 2;
        sqx = sp[0]; sqy = sp[1];
    }

    // Q fragments: rows q2, q2+8, head h2
    v2f qf[2][4];
#pragma unroll
    for (int i = 0; i < 2; ++i) {
        const float* qp = Qbuf + (b * LEN + q0 + q2 + 8 * i) * 64 + h2 * 8;
        float4 qa = *(const float4*)qp;
        float4 qb = *(const float4*)(qp + 4);
        qf[i][0] = (v2f){qa.x, qa.y}; qf[i][1] = (v2f){qa.z, qa.w};
        qf[i][2] = (v2f){qb.x, qb.y}; qf[i][3] = (v2f){qb.z, qb.w};
    }

    float m[2] = {-1e30f, -1e30f};
    float l[2] = {};
    v2f oacc[2][4] = {};

    for (int kt = ks * 4; kt < ks * 4 + 4; ++kt) {
        __syncthreads();
        {   // K/V tile load (32 x 64 each), float4 staging, stride 68
            int kr = t >> 3, j = (t & 7) * 8;
            const float* ksrc = Kbuf + (b * LEN + kt * 32 + kr) * 64 + j;
            const float* vsrc = Vbuf + (b * LEN + kt * 32 + kr) * 64 + j;
            *(float4*)&Ks[kr * 68 + j]     = *(const float4*)ksrc;
            *(float4*)&Ks[kr * 68 + j + 4] = *(const float4*)(ksrc + 4);
            *(float4*)&Vs[kr * 68 + j]     = *(const float4*)vsrc;
            *(float4*)&Vs[kr * 68 + j + 4] = *(const float4*)(vsrc + 4);
        }
        {   // distances + segment, packed; thread covers pairs (pq, 2pk), (pq, 2pk+1)
            float4 kc = *(const float4*)(sk_src + (b * LEN + kt * 32 + pk * 2) * 2);
            float dx0 = sqx - kc.x, dy0 = sqy - kc.y;
            float dx1 = sqx - kc.z, dy1 = sqy - kc.w;
            float d0 = dx0 * dx0 + dy0 * dy0;
            float d1 = dx1 * dx1 + dy1 * dy1;
            int s0 = 0, s1 = 0;
#pragma unroll
            for (int j = 0; j < 16; ++j) { s0 += (d0 > bp[j]); s1 += (d1 > bp[j]); }
            Sds[(pk * 2) * 17 + pq]     = __uint_as_float((__float_as_uint(d0) & ~31u) | s0);
            Sds[(pk * 2 + 1) * 17 + pq] = __uint_as_float((__float_as_uint(d1) & ~31u) | s1);
        }
        __syncthreads();

        // pass 1: scores (log2 domain) for 8 keys x 2 q's
        float sv[2][8];
#pragma unroll
        for (int j = 0; j < 8; ++j) {
            int k = par + 4 * j;
            const v2f* kf = (const v2f*)&Ks[k * 68 + h2 * 8];
            v2f k0 = kf[0], k1 = kf[1], k2 = kf[2], k3 = kf[3];
#pragma unroll
            for (int i = 0; i < 2; ++i) {
                unsigned u = __float_as_uint(Sds[k * 17 + q2 + 8 * i]);
                float dv = __uint_as_float(u & ~31u);
                v2f pv_ = pw[(u & 31u) * 8 + h2];
                v2f acc = qf[i][0] * k0;
                acc += qf[i][1] * k1;
                acc += qf[i][2] * k2;
                acc += qf[i][3] * k3;
                sv[i][j] = (acc.x + acc.y) * SCALE_L2E + (pv_.x * dv + pv_.y);
            }
        }
        // online softmax update per q
#pragma unroll
        for (int i = 0; i < 2; ++i) {
            float tm = m[i];
#pragma unroll
            for (int j = 0; j < 8; ++j) tm = fmaxf(tm, sv[i][j]);
            float alpha = exp2f(m[i] - tm);
            l[i] *= alpha;
            v2f av = (v2f){alpha, alpha};
#pragma unroll
            for (int c = 0; c < 4; ++c) oacc[i][c] *= av;
            m[i] = tm;
#pragma unroll
            for (int j = 0; j < 8; ++j) {
                float p = exp2f(sv[i][j] - tm);
                sv[i][j] = p;
                l[i] += p;
            }
        }
        // pass 2: PV
#pragma unroll
        for (int j = 0; j < 8; ++j) {
            int k = par + 4 * j;
            const v2f* vf = (const v2f*)&Vs[k * 68 + h2 * 8];
            v2f v0 = vf[0], v1 = vf[1], v2 = vf[2], v3 = vf[3];
#pragma unroll
            for (int i = 0; i < 2; ++i) {
                float p = sv[i][j];
                v2f pp = (v2f){p, p};
                oacc[i][0] += pp * v0;
                oacc[i][1] += pp * v1;
                oacc[i][2] += pp * v2;
                oacc[i][3] += pp * v3;
            }
        }
    }

    // butterfly merge across par (xor 1,2 within wave)
#pragma unroll
    for (int st = 1; st <= 2; st <<= 1) {
#pragma unroll
        for (int i = 0; i < 2; ++i) {
            float mo = __shfl_xor(m[i], st);
            float Mx = fmaxf(m[i], mo);
            float a0 = exp2f(m[i] - Mx), a1 = exp2f(mo - Mx);
            float lo = __shfl_xor(l[i], st);
            l[i] = l[i] * a0 + lo * a1;
#pragma unroll
            for (int c = 0; c < 4; ++c) {
                v2f x = oacc[i][c];
                float x0 = x.x * a0 + __shfl_xor(x.x, st) * a1;
                float x1 = x.y * a0 + __shfl_xor(x.y, st) * a1;
                oacc[i][c] = (v2f){x0, x1};
            }
            m[i] = Mx;
        }
    }

    // write normalized bf16 partials, INTERLEAVED layout: row*384 + h*48 + ks*6
    // (the 8 ks-chunks of one (row,h) are complementary 24B pieces -> full-line
    //  merge in L2, no RFO amplification — R4-proven mechanism)
    if (par == 0) {
#pragma unroll
        for (int i = 0; i < 2; ++i) {
            float inv = 1.f / l[i];
            float lse = m[i] + log2f(l[i]);
            int row = q0 + q2 + 8 * i;
            float* p = ws + OFF_PART + (z * LEN + row) * 384 + h2 * 48 + ks * 6;
            *(v2f*)(p)     = (v2f){ pack2(oacc[i][0].x * inv, oacc[i][0].y * inv),
                                    pack2(oacc[i][1].x * inv, oacc[i][1].y * inv) };
            *(v2f*)(p + 2) = (v2f){ pack2(oacc[i][2].x * inv, oacc[i][2].y * inv),
                                    pack2(oacc[i][3].x * inv, oacc[i][3].y * inv) };
            *(v2f*)(p + 4) = (v2f){ lse, 0.f };
        }
    }
}

// ---- fused: merge + Wo + resid + LN + FFN + resid + LN + next-QKV / head ----
// grid (1024, kind=2), 64 threads (single wave), 2 rows per block.
__global__ __launch_bounds__(64) void k_fuse(int blk, float* ws, const void* ns_raw, void* out_raw) {
    __shared__ float xo[2][64];
    __shared__ float xsm[2][64];
    __shared__ float hs[2][128];
    __shared__ float xn[2][64];
    const int t = threadIdx.x;
    const int kind = blockIdx.y;
    const int g = blockIdx.x;
    const int rg0 = g * 2, rg1 = g * 2 + 1;
    float* io = ws + (kind == 0 ? OFF_QVS : OFF_KVS);

    // ---- stage A: merge 8 K-split partials; thread (h = t>>3, d = t&7), 2 rows ----
    {
        int h = t >> 3, d = t & 7;
#pragma unroll
        for (int r = 0; r < 2; ++r) {
            int rg = g * 2 + r, b = rg >> 10, row = rg & 1023, z = kind * 2 + b;
            const float* base = ws + OFF_PART + (z * LEN + row) * 384 + h * 48;
            float ls[8];
            float M = -1e30f;
#pragma unroll
            for (int k2 = 0; k2 < 8; ++k2) { ls[k2] = base[k2 * 6 + 4]; M = fmaxf(M, ls[k2]); }
            float den = 0.f, num = 0.f;
#pragma unroll
            for (int k2 = 0; k2 < 8; ++k2) {
                float e = exp2f(ls[k2] - M);
                den += e;
                float pf = base[k2 * 6 + (d >> 1)];
                float o = (d & 1) ? unhi(pf) : unlo(pf);
                num += e * o;
            }
            xo[r][h * 8 + d] = num / den;
        }
    }
    __syncthreads();

    float xs0, xs1;   // attn-normed value at col t, rows 0/1
    // ---- stage B: Wo + residual + LN ----
    {
        const float* Wo = ws + I_WO + blk * 4096;
        float bo = ws[I_BO + blk * 64 + t];
        float a0 = bo, a1 = bo;
#pragma unroll 8
        for (int k = 0; k < 64; ++k) {
            float w = Wo[k * 64 + t];
            a0 += xo[0][k] * w;
            a1 += xo[1][k] * w;
        }
        a0 += io[rg0 * 64 + t];
        a1 += io[rg1 * 64 + t];
        float s0 = a0, q0_ = a0 * a0, s1 = a1, q1_ = a1 * a1;
#pragma unroll
        for (int off = 1; off < 64; off <<= 1) {
            s0 += __shfl_xor(s0, off); q0_ += __shfl_xor(q0_, off);
            s1 += __shfl_xor(s1, off); q1_ += __shfl_xor(q1_, off);
        }
        float mu0 = s0 * (1.f / 64.f), var0 = q0_ * (1.f / 64.f) - mu0 * mu0;
        float mu1 = s1 * (1.f / 64.f), var1 = q1_ * (1.f / 64.f) - mu1 * mu1;
        float rs0 = rsqrtf(fmaxf(var0, 0.f) + 1e-6f);
        float rs1 = rsqrtf(fmaxf(var1, 0.f) + 1e-6f);
        float nsv = ws[I_NS + blk * 64 + t], nbv = ws[I_NB + blk * 64 + t];
        xs0 = (a0 - mu0) * rs0 * nsv + nbv;
        xs1 = (a1 - mu1) * rs1 * nsv + nbv;
        xsm[0][t] = xs0; xsm[1][t] = xs1;
    }
    __syncthreads();

    // ---- stage C: FFN1 (2 cols x 2 rows) ----
    {
        const float* W1 = ws + I_FW1 + blk * 8192;
        float b0 = ws[I_FB1 + blk * 128 + t], b1 = ws[I_FB1 + blk * 128 + t + 64];
        float a00 = b0, a01 = b1, a10 = b0, a11 = b1;
#pragma unroll 8
        for (int k = 0; k < 64; ++k) {
            float w0 = W1[k * 128 + t], w1 = W1[k * 128 + t + 64];
            float x0 = xsm[0][k], x1 = xsm[1][k];
            a00 += x0 * w0; a01 += x0 * w1;
            a10 += x1 * w0; a11 += x1 * w1;
        }
        hs[0][t] = fmaxf(a00, 0.f); hs[0][t + 64] = fmaxf(a01, 0.f);
        hs[1][t] = fmaxf(a10, 0.f); hs[1][t + 64] = fmaxf(a11, 0.f);
    }
    __syncthreads();

    // ---- stage D: FFN2 + residual + LN ----
    float v00, v10;
    {
        const float* W2 = ws + I_FW2 + blk * 8192;
        float b2 = ws[I_FB2 + blk * 64 + t];
        float a0 = b2, a1 = b2;
#pragma unroll 8
        for (int k = 0; k < 128; ++k) {
            float w = W2[k * 64 + t];
            a0 += hs[0][k] * w;
            a1 += hs[1][k] * w;
        }
        a0 += xs0; a1 += xs1;
        float s0 = a0, q0_ = a0 * a0, s1 = a1, q1_ = a1 * a1;
#pragma unroll
        for (int off = 1; off < 64; off <<= 1) {
            s0 += __shfl_xor(s0, off); q0_ += __shfl_xor(q0_, off);
            s1 += __shfl_xor(s1, off); q1_ += __shfl_xor(q1_, off);
        }
        float mu0 = s0 * (1.f / 64.f), var0 = q0_ * (1.f / 64.f) - mu0 * mu0;
        float mu1 = s1 * (1.f / 64.f), var1 = q1_ * (1.f / 64.f) - mu1 * mu1;
        float rs0 = rsqrtf(fmaxf(var0, 0.f) + 1e-6f);
        float rs1 = rsqrtf(fmaxf(var1, 0.f) + 1e-6f);
        float nsv = ws[I_NS + blk * 64 + t], nbv = ws[I_NB + blk * 64 + t];
        v00 = (a0 - mu0) * rs0 * nsv + nbv;
        v10 = (a1 - mu1) * rs1 * nsv + nbv;
        io[rg0 * 64 + t] = v00;
        io[rg1 * 64 + t] = v10;
        xn[0][t] = v00; xn[1][t] = v10;
    }
    __syncthreads();

    if (blk < 5) {
        // ---- stage E: next-layer QKV ----
        const int nb_ = blk + 1;
        if (kind == 0) {
            const float* WQ = ws + I_WQ + nb_ * 4096;
            float bq = ws[I_BQ + nb_ * 64 + t];
            float a0 = bq, a1 = bq;
#pragma unroll 8
            for (int k = 0; k < 64; ++k) {
                float w = WQ[k * 64 + t];
                a0 += xn[0][k] * w;
                a1 += xn[1][k] * w;
            }
            ws[OFF_Q1 + rg0 * 64 + t] = a0;
            ws[OFF_Q1 + rg1 * 64 + t] = a1;
        } else {
            const float* WQ = ws + I_WQ + nb_ * 4096;
            const float* WK = ws + I_WK + nb_ * 4096;
            const float* WV = ws + I_WV + nb_ * 4096;
            float bq = ws[I_BQ + nb_ * 64 + t];
            float bk = ws[I_BK + nb_ * 64 + t];
            float bv = ws[I_BV + nb_ * 64 + t];
            float q0a = bq, q1a = bq, k0a = bk, k1a = bk, v0a = bv, v1a = bv;
#pragma unroll 4
            for (int k = 0; k < 64; ++k) {
                float wq = WQ[k * 64 + t], wk = WK[k * 64 + t], wv = WV[k * 64 + t];
                float x0 = xn[0][k], x1 = xn[1][k];
                q0a += x0 * wq; q1a += x1 * wq;
                k0a += x0 * wk; k1a += x1 * wk;
                v0a += x0 * wv; v1a += x1 * wv;
            }
            ws[OFF_Q2 + rg0 * 64 + t] = q0a; ws[OFF_Q2 + rg1 * 64 + t] = q1a;
            ws[OFF_KB + rg0 * 64 + t] = k0a; ws[OFF_KB + rg1 * 64 + t] = k1a;
            ws[OFF_VB + rg0 * 64 + t] = v0a; ws[OFF_VB + rg1 * 64 + t] = v1a;
        }
    } else if (kind == 0) {
        // ---- stage F: final LN + head MLP + split/exp ----
        {
            float s0 = v00, q0_ = v00 * v00, s1 = v10, q1_ = v10 * v10;
#pragma unroll
            for (int off = 1; off < 64; off <<= 1) {
                s0 += __shfl_xor(s0, off); q0_ += __shfl_xor(q0_, off);
                s1 += __shfl_xor(s1, off); q1_ += __shfl_xor(q1_, off);
            }
            float mu0 = s0 * (1.f / 64.f), var0 = q0_ * (1.f / 64.f) - mu0 * mu0;
            float mu1 = s1 * (1.f / 64.f), var1 = q1_ * (1.f / 64.f) - mu1 * mu1;
            float rs0 = rsqrtf(fmaxf(var0, 0.f) + 1e-6f);
            float rs1 = rsqrtf(fmaxf(var1, 0.f) + 1e-6f);
            float fns = ws[I_FNS + t], fnb = ws[I_FNB + t];
            xsm[0][t] = (v00 - mu0) * rs0 * fns + fnb;
            xsm[1][t] = (v10 - mu1) * rs1 * fns + fnb;
        }
        __syncthreads();
        {
            const float* W1 = ws + I_HW1;
            float b0 = ws[I_HB1 + t], b1 = ws[I_HB1 + t + 64];
            float a00 = b0, a01 = b1, a10 = b0, a11 = b1;
#pragma unroll 8
            for (int k = 0; k < 64; ++k) {
                float w0 = W1[k * 128 + t], w1 = W1[k * 128 + t + 64];
                float x0 = xsm[0][k], x1 = xsm[1][k];
                a00 += x0 * w0; a01 += x0 * w1;
                a10 += x1 * w0; a11 += x1 * w1;
            }
            hs[0][t] = fmaxf(a00, 0.f); hs[0][t + 64] = fmaxf(a01, 0.f);
            hs[1][t] = fmaxf(a10, 0.f); hs[1][t + 64] = fmaxf(a11, 0.f);
        }
        __syncthreads();
        if (t < 4) {
            int rr = t >> 1, c = t & 1;
            float a = ws[I_HB2 + c];
            for (int k = 0; k < 128; ++k) a += hs[rr][k] * ws[I_HW2 + k * 2 + c];
            float v = c ? exp2f(a * 0.7213475204444817f) : a;   // exp(a/2)
            int rgg = g * 2 + rr;
            int idx = c ? (N2 + rgg) : rgg;
            unsigned u0 = *(const unsigned*)ns_raw;
            if (u0 == 0x3F803F80u) ((bf16*)out_raw)[idx] = __float2bfloat16(v);
            else                   ((float*)out_raw)[idx] = v;
        }
    }
}

extern "C" void kernel_launch(void* const* d_in, const int* in_sizes, int n_in,
                              void* d_out, int out_size, void* d_ws, size_t ws_size,
                              hipStream_t stream) {
    float* ws = (float*)d_ws;

    InPtrs ptrs;
    for (int i = 0; i < 32; ++i) ptrs.p[i] = d_in[i];

    k_cvt<<<dim3(8, 32), 256, 0, stream>>>(ptrs, ws);
    k_pw<<<6, 256, 0, stream>>>(ws);
    k_embed<<<4096, 256, 0, stream>>>(ws);
    k_qkv<<<2048, 256, 0, stream>>>(0, ws);
    for (int i = 0; i < 6; ++i) {
        k_attn<<<dim3(64, 8, 4), 256, 0, stream>>>(i, ws);
        k_fuse<<<dim3(1024, 2), 64, 0, stream>>>(i, ws, d_in[24], d_out);
    }
}

// Round 9
// 553.893 us; speedup vs baseline: 1.2865x; 1.2865x over previous
//
#include <hip/hip_runtime.h>
#include <hip/hip_bf16.h>

typedef __hip_bfloat16 bf16;
typedef float v2f __attribute__((ext_vector_type(2)));

#define LEN 1024
#define N2 2048            // B * L rows
#define SCALE_L2E 0.5100697918f   // (1/sqrt(8)) * log2(e)

// ---- converted-input float offsets in ws ----
#define I_SCTX   0
#define I_FCTX   4096
#define I_STEST  6144
#define I_OBS    10240
#define I_EW1    10248
#define I_EB1    12040
#define I_EW2    12296
#define I_EB2    28680
#define I_WQ     28744
#define I_BQ     53320
#define I_WK     53704
#define I_BK     78280
#define I_WV     78664
#define I_BV     103240
#define I_WO     103624
#define I_BO     128200
#define I_FW1    128584
#define I_FB1    177736
#define I_FW2    178504
#define I_FB2    227656
#define I_BW1    228040
#define I_BB1    228136
#define I_BW2    228232
#define I_BB2    229000
#define I_NS     229048
#define I_NB     229432
#define I_FNS    229816
#define I_FNB    229880
#define I_HW1    229944
#define I_HB1    238136
#define I_HW2    238264
#define I_HB2    238520

#define OFF_PW   240256    // 6 layers x 288 floats
#define OFF_QVS  262144
#define OFF_KVS  393216
#define OFF_Q1   524288
#define OFF_Q2   655360
#define OFF_KB   786432
#define OFF_VB   917504
#define OFF_PART 1048576   // partials: [z=4][row=1024][h=8][ks=6][8] floats = 1.57M (proven budget)
// entry (32 B, float4-aligned): [0..3] = 4x packed-bf16 normalized O, [4] = lse, [5..7] pad
// R4-replica write geometry: 16B stores, 192 B per (row,h) region, 192 B h-stride.

__constant__ int C_OFFS[33] = {
    0, 4096, 6144, 10240, 10248, 12040, 12296, 28680, 28744, 53320, 53704,
    78280, 78664, 103240, 103624, 128200, 128584, 177736, 178504, 227656,
    228040, 228136, 228232, 229000, 229048, 229432, 229816, 229880, 229944,
    238136, 238264, 238520, 238522 };

struct InPtrs { const void* p[32]; };

__device__ __forceinline__ float pack2(float a, float b) {
    __hip_bfloat16 ha = __float2bfloat16(a), hb = __float2bfloat16(b);
    unsigned ua = *(unsigned short*)&ha, ub = *(unsigned short*)&hb;
    return __uint_as_float(ua | (ub << 16));
}
__device__ __forceinline__ float unlo(float f) {
    return __uint_as_float(__float_as_uint(f) << 16);
}
__device__ __forceinline__ float unhi(float f) {
    return __uint_as_float(__float_as_uint(f) & 0xffff0000u);
}

// ---------------- convert all inputs to f32 in ws ----------------
__global__ __launch_bounds__(256) void k_cvt(InPtrs ptrs, float* ws) {
    const unsigned u0 = *(const unsigned*)ptrs.p[24];   // norm_scale = ones
    const int isbf = (u0 == 0x3F803F80u);
    const int i = blockIdx.y;
    const int o0 = C_OFFS[i], n = C_OFFS[i + 1] - o0;
    const void* src = ptrs.p[i];
    for (int j = blockIdx.x * 256 + threadIdx.x; j < n; j += gridDim.x * 256) {
        float v = isbf ? __bfloat162float(((const bf16*)src)[j])
                       : ((const float*)src)[j];
        ws[o0 + j] = v;
    }
}

// ---- piecewise-linear form of the distance-bias MLP, per layer ----
__global__ __launch_bounds__(256) void k_pw(float* ws) {
    const int L = blockIdx.x, t = threadIdx.x;
    __shared__ float w1s[16], b1s[16], bps[16];
    __shared__ int rnk[16];
    if (t < 16) {
        float w = ws[I_BW1 + L * 16 + t], b0 = ws[I_BB1 + L * 16 + t];
        w1s[t] = w; b1s[t] = b0;
        bps[t] = (w != 0.f) ? (-b0 / w) : 1e30f;
    }
    __syncthreads();
    if (t < 16) {
        float me = bps[t]; int r = 0;
        for (int j = 0; j < 16; ++j) {
            float o = bps[j];
            if (o < me || (o == me && j < t)) ++r;
        }
        rnk[t] = r;
    }
    __syncthreads();
    if (t < 16) ws[OFF_PW + L * 288 + 272 + rnk[t]] = bps[t];
    if (t < 136) {
        int s = t >> 3, h = t & 7;
        float slope = 0.f, inter = ws[I_BB2 + L * 8 + h];
        for (int j = 0; j < 16; ++j) {
            float w = w1s[j];
            bool act = (w > 0.f) ? (rnk[j] < s)
                     : (w < 0.f) ? (rnk[j] >= s)
                                 : (b1s[j] > 0.f);
            if (act) {
                float w2v = ws[I_BW2 + L * 128 + j * 8 + h];
                slope += w * w2v;
                inter += b1s[j] * w2v;
            }
        }
        const float LOG2E = 1.4426950408889634f;
        ws[OFF_PW + L * 288 + (s * 8 + h) * 2]     = slope * LOG2E;
        ws[OFF_PW + L * 288 + (s * 8 + h) * 2 + 1] = inter * LOG2E;
    }
}

// ---------------- embed MLP: 7 -> 256 relu -> 64 ----------------
__global__ __launch_bounds__(256) void k_embed(float* ws) {
    __shared__ float hbuf[256];
    __shared__ float red[256];
    int r = blockIdx.x, t = threadIdx.x;
    bool is_ctx = (r < N2);
    int rr = is_ctx ? r : r - N2;
    const float* ob = ws + I_OBS + (is_ctx ? 4 : 0);
    const float* s  = ws + (is_ctx ? I_SCTX : I_STEST);
    float in[7];
    in[0] = ob[0]; in[1] = ob[1]; in[2] = ob[2]; in[3] = ob[3];
    in[4] = s[rr * 2]; in[5] = s[rr * 2 + 1];
    in[6] = is_ctx ? ws[I_FCTX + rr] : 0.f;

    float acc = ws[I_EB1 + t];
#pragma unroll
    for (int i = 0; i < 7; ++i) acc += in[i] * ws[I_EW1 + i * 256 + t];
    hbuf[t] = fmaxf(acc, 0.f);
    __syncthreads();

    int d = t & 63, p = t >> 6;
    float a2 = 0.f;
#pragma unroll 8
    for (int j = p * 64; j < p * 64 + 64; ++j) a2 += hbuf[j] * ws[I_EW2 + j * 64 + d];
    red[t] = a2;
    __syncthreads();
    if (t < 64) {
        float o = red[t] + red[64 + t] + red[128 + t] + red[192 + t] + ws[I_EB2 + t];
        float* dst = ws + (is_ctx ? OFF_KVS : OFF_QVS);
        dst[rr * 64 + t] = o;
    }
}

// ---------------- QKV projections (layer 0 only) ----------------
__global__ __launch_bounds__(256) void k_qkv(int blk, float* ws) {
    __shared__ float xs[2][64];
    int r = blockIdx.x, t = threadIdx.x;
    if (t < 64)       xs[0][t] = ws[OFF_QVS + r * 64 + t];
    else if (t < 128) xs[1][t - 64] = ws[OFF_KVS + r * 64 + (t - 64)];
    __syncthreads();
    int o = t >> 6, d = t & 63;
    const float* x = (o == 0) ? xs[0] : xs[1];
    const float* W; const float* bb; float* dst;
    if (o <= 1)      { W = ws + I_WQ + blk * 4096; bb = ws + I_BQ + blk * 64; dst = ws + (o == 0 ? OFF_Q1 : OFF_Q2); }
    else if (o == 2) { W = ws + I_WK + blk * 4096; bb = ws + I_BK + blk * 64; dst = ws + OFF_KB; }
    else             { W = ws + I_WV + blk * 4096; bb = ws + I_BV + blk * 64; dst = ws + OFF_VB; }
    float acc = bb[d];
#pragma unroll 8
    for (int k = 0; k < 64; ++k) acc += x[k] * W[k * 64 + d];
    dst[r * 64 + d] = acc;
}

// ---- attention, K-split 6, R6 read path, R4-geometry float4 partial writes ----
// grid (qt=64, ks=6, z=4), z = kind*2 + b. Tiles: ks<2 -> 6 tiles else 5.
// thread = (q2 = t>>4 in [0,16), h2 = (t>>1)&7, par = t&1); keys k = par + 2j.
__global__ __launch_bounds__(256, 7) void k_attn(int blk, float* ws) {
    __shared__ float Ks[2176];     // 32 x 68
    __shared__ float Vs[2176];
    __shared__ float Sds[544];     // [k*17+q]: d with seg packed in low 5 mantissa bits
    __shared__ v2f   pw[136];

    const int t = threadIdx.x;
    const int qt = blockIdx.x, ks = blockIdx.y, z = blockIdx.z;
    const int b = z & 1, kind = z >> 1;
    const int q0 = qt * 16;
    const float* Qbuf = ws + (kind == 0 ? OFF_Q1 : OFF_Q2);
    const float* Kbuf = ws + OFF_KB;
    const float* Vbuf = ws + OFF_VB;
    const float* sq_src = ws + (kind == 0 ? I_STEST : I_SCTX);
    const float* sk_src = ws + I_SCTX;
    const float* pwg = ws + OFF_PW + blk * 288;   // uniform -> scalar loads

    float bp[16];
#pragma unroll
    for (int j = 0; j < 16; ++j) bp[j] = pwg[272 + j];

    if (t < 136) pw[t] = (v2f){ pwg[t * 2], pwg[t * 2 + 1] };

    const int q2 = t >> 4, h2 = (t >> 1) & 7, par = t & 1;
    // Sds precompute mapping (independent)
    const int pq = t >> 4, pk = t & 15;
    float sqx, sqy;
    {
        const float* sp = sq_src + (b * LEN + q0 + pq) * 2;
        sqx = sp[0]; sqy = sp[1];
    }

    // Q fragment in registers
    v2f qf[4];
    {
        const float* qp = Qbuf + (b * LEN + q0 + q2) * 64 + h2 * 8;
        float4 qa = *(const float4*)qp;
        float4 qb = *(const float4*)(qp + 4);
        qf[0] = (v2f){qa.x, qa.y}; qf[1] = (v2f){qa.z, qa.w};
        qf[2] = (v2f){qb.x, qb.y}; qf[3] = (v2f){qb.z, qb.w};
    }

    float m = -1e30f, lsum = 0.f;
    v2f oacc[4] = {};

    const int kt0 = ks * 5 + (ks < 2 ? ks : 2);
    const int ktn = (ks < 2) ? 6 : 5;
    for (int kt = kt0; kt < kt0 + ktn; ++kt) {
        __syncthreads();
        {   // K/V tile load (32 x 64 each), float4 staging, stride 68
            int kr = t >> 3, j = (t & 7) * 8;
            const float* ksrc = Kbuf + (b * LEN + kt * 32 + kr) * 64 + j;
            const float* vsrc = Vbuf + (b * LEN + kt * 32 + kr) * 64 + j;
            *(float4*)&Ks[kr * 68 + j]     = *(const float4*)ksrc;
            *(float4*)&Ks[kr * 68 + j + 4] = *(const float4*)(ksrc + 4);
            *(float4*)&Vs[kr * 68 + j]     = *(const float4*)vsrc;
            *(float4*)&Vs[kr * 68 + j + 4] = *(const float4*)(vsrc + 4);
        }
        {   // distances + segment, packed; thread covers pairs (pq, 2pk), (pq, 2pk+1)
            float4 kc = *(const float4*)(sk_src + (b * LEN + kt * 32 + pk * 2) * 2);
            float dx0 = sqx - kc.x, dy0 = sqy - kc.y;
            float dx1 = sqx - kc.z, dy1 = sqy - kc.w;
            float d0 = dx0 * dx0 + dy0 * dy0;
            float d1 = dx1 * dx1 + dy1 * dy1;
            int s0 = 0, s1 = 0;
#pragma unroll
            for (int j = 0; j < 16; ++j) { s0 += (d0 > bp[j]); s1 += (d1 > bp[j]); }
            Sds[(pk * 2) * 17 + pq]     = __uint_as_float((__float_as_uint(d0) & ~31u) | s0);
            Sds[(pk * 2 + 1) * 17 + pq] = __uint_as_float((__float_as_uint(d1) & ~31u) | s1);
        }
        __syncthreads();

        // pass 1: scores (log2 domain) for 16 keys of parity `par`
        float sv[16];
#pragma unroll
        for (int j = 0; j < 16; ++j) {
            int k = par + 2 * j;
            unsigned u = __float_as_uint(Sds[k * 17 + q2]);
            float dv = __uint_as_float(u & ~31u);
            v2f pv_ = pw[(u & 31u) * 8 + h2];
            const v2f* kf = (const v2f*)&Ks[k * 68 + h2 * 8];
            v2f acc = qf[0] * kf[0];
            acc += qf[1] * kf[1];
            acc += qf[2] * kf[2];
            acc += qf[3] * kf[3];
            sv[j] = (acc.x + acc.y) * SCALE_L2E + (pv_.x * dv + pv_.y);
        }
        float tm = m;
#pragma unroll
        for (int j = 0; j < 16; ++j) tm = fmaxf(tm, sv[j]);
        float alpha = exp2f(m - tm);
        lsum *= alpha;
        v2f av = (v2f){alpha, alpha};
#pragma unroll
        for (int c = 0; c < 4; ++c) oacc[c] *= av;
#pragma unroll
        for (int j = 0; j < 16; ++j) {
            int k = par + 2 * j;
            float p = exp2f(sv[j] - tm);
            lsum += p;
            const v2f* vf = (const v2f*)&Vs[k * 68 + h2 * 8];
            v2f pp = (v2f){p, p};
            oacc[0] += pp * vf[0];
            oacc[1] += pp * vf[1];
            oacc[2] += pp * vf[2];
            oacc[3] += pp * vf[3];
        }
        m = tm;
    }

    // merge par states (lane^1), write 32 B entry with TWO float4 stores
    {
        float mo = __shfl_xor(m, 1);
        float Mx = fmaxf(m, mo);
        float a0 = exp2f(m - Mx), a1 = exp2f(mo - Mx);
        float lo = __shfl_xor(lsum, 1);
        float Lt = lsum * a0 + lo * a1;
        float ov[8];
#pragma unroll
        for (int c = 0; c < 4; ++c) {
            v2f x = oacc[c];
            ov[2 * c]     = x.x * a0 + __shfl_xor(x.x, 1) * a1;
            ov[2 * c + 1] = x.y * a0 + __shfl_xor(x.y, 1) * a1;
        }
        if (par == 0) {
            float inv = 1.f / Lt;
            float lse = Mx + log2f(Lt);
            float* p = ws + OFF_PART + (z * LEN + q0 + q2) * 384 + (h2 * 6 + ks) * 8;
            *(float4*)(p)     = make_float4(pack2(ov[0] * inv, ov[1] * inv),
                                            pack2(ov[2] * inv, ov[3] * inv),
                                            pack2(ov[4] * inv, ov[5] * inv),
                                            pack2(ov[6] * inv, ov[7] * inv));
            *(float4*)(p + 4) = make_float4(lse, 0.f, 0.f, 0.f);
        }
    }
}

// ---- fused: merge + Wo + resid + LN + FFN + resid + LN + next-QKV / head ----
// grid (512, kind=2), 256 threads, 4 rows per block; wave w owns row w.
__global__ __launch_bounds__(256) void k_fuse(int blk, float* ws, const void* ns_raw, void* out_raw) {
    __shared__ float raw[1536];
    __shared__ float xo[256];
    __shared__ float xsm[256];
    __shared__ float hs[512];
    __shared__ float xn[256];
    const int t = threadIdx.x;
    const int kind = blockIdx.y;
    const int r0 = blockIdx.x * 4;
    const int bq_ = r0 >> 10;                 // batch (uniform per block)
    const int z = kind * 2 + bq_;
    const int row0 = r0 & 1023;
    float* io = ws + (kind == 0 ? OFF_QVS : OFF_KVS);

    // ---- stage A: load 4 rows of partials (contiguous 6 KB), merge 6 K-splits ----
    {
        const float* pbase = ws + OFF_PART + (z * LEN + row0) * 384;
        for (int i = t; i < 384; i += 256)
            ((float4*)raw)[i] = ((const float4*)pbase)[i];
    }
    __syncthreads();
    {
        int r = t >> 6, h = (t >> 3) & 7, d = t & 7;
        const float* e = raw + r * 384 + h * 48;   // 6 entries x 8 floats
        float M = -1e30f;
#pragma unroll
        for (int k2 = 0; k2 < 6; ++k2) M = fmaxf(M, e[k2 * 8 + 4]);
        float den = 0.f, num = 0.f;
#pragma unroll
        for (int k2 = 0; k2 < 6; ++k2) {
            float w = exp2f(e[k2 * 8 + 4] - M);
            den += w;
            float pf = e[k2 * 8 + (d >> 1)];
            num += w * ((d & 1) ? unhi(pf) : unlo(pf));
        }
        xo[r * 64 + h * 8 + d] = num / den;
    }
    __syncthreads();

    const int r = t >> 6, c = t & 63;
    const int rg = r0 + r;
    float xs_;

    // ---- stage B: Wo + residual + LN (wave-wide shuffle) ----
    {
        const float* Wo = ws + I_WO + blk * 4096;
        float a = ws[I_BO + blk * 64 + c];
#pragma unroll 8
        for (int k = 0; k < 64; ++k) a += xo[r * 64 + k] * Wo[k * 64 + c];
        a += io[rg * 64 + c];
        float s = a, s2 = a * a;
#pragma unroll
        for (int off = 1; off < 64; off <<= 1) { s += __shfl_xor(s, off); s2 += __shfl_xor(s2, off); }
        float mu = s * (1.f / 64.f);
        float var = s2 * (1.f / 64.f) - mu * mu;
        float rs = rsqrtf(fmaxf(var, 0.f) + 1e-6f);
        xs_ = (a - mu) * rs * ws[I_NS + blk * 64 + c] + ws[I_NB + blk * 64 + c];
        xsm[r * 64 + c] = xs_;
    }
    __syncthreads();

    // ---- stage C: FFN1 (2 cols/thread) ----
    {
        const float* W1 = ws + I_FW1 + blk * 8192;
        float a0 = ws[I_FB1 + blk * 128 + c], a1 = ws[I_FB1 + blk * 128 + c + 64];
#pragma unroll 8
        for (int k = 0; k < 64; ++k) {
            float x = xsm[r * 64 + k];
            a0 += x * W1[k * 128 + c];
            a1 += x * W1[k * 128 + c + 64];
        }
        hs[r * 128 + c] = fmaxf(a0, 0.f);
        hs[r * 128 + c + 64] = fmaxf(a1, 0.f);
    }
    __syncthreads();

    // ---- stage D: FFN2 + residual + LN ----
    float v_;
    {
        const float* W2 = ws + I_FW2 + blk * 8192;
        float a = ws[I_FB2 + blk * 64 + c];
#pragma unroll 8
        for (int k = 0; k < 128; ++k) a += hs[r * 128 + k] * W2[k * 64 + c];
        a += xs_;
        float s = a, s2 = a * a;
#pragma unroll
        for (int off = 1; off < 64; off <<= 1) { s += __shfl_xor(s, off); s2 += __shfl_xor(s2, off); }
        float mu = s * (1.f / 64.f);
        float var = s2 * (1.f / 64.f) - mu * mu;
        float rs = rsqrtf(fmaxf(var, 0.f) + 1e-6f);
        v_ = (a - mu) * rs * ws[I_NS + blk * 64 + c] + ws[I_NB + blk * 64 + c];
        io[rg * 64 + c] = v_;
        xn[r * 64 + c] = v_;
    }
    __syncthreads();

    if (blk < 5) {
        // ---- stage E: next-layer QKV ----
        const int nb_ = blk + 1;
        if (kind == 0) {
            const float* WQ = ws + I_WQ + nb_ * 4096;
            float a = ws[I_BQ + nb_ * 64 + c];
#pragma unroll 8
            for (int k = 0; k < 64; ++k) a += xn[r * 64 + k] * WQ[k * 64 + c];
            ws[OFF_Q1 + rg * 64 + c] = a;
        } else {
            const float* WQ = ws + I_WQ + nb_ * 4096;
            const float* WK = ws + I_WK + nb_ * 4096;
            const float* WV = ws + I_WV + nb_ * 4096;
            float aq = ws[I_BQ + nb_ * 64 + c];
            float ak = ws[I_BK + nb_ * 64 + c];
            float av = ws[I_BV + nb_ * 64 + c];
#pragma unroll 4
            for (int k = 0; k < 64; ++k) {
                float x = xn[r * 64 + k];
                aq += x * WQ[k * 64 + c];
                ak += x * WK[k * 64 + c];
                av += x * WV[k * 64 + c];
            }
            ws[OFF_Q2 + rg * 64 + c] = aq;
            ws[OFF_KB + rg * 64 + c] = ak;
            ws[OFF_VB + rg * 64 + c] = av;
        }
    } else if (kind == 0) {
        // ---- stage F: final LN + head MLP + split/exp ----
        {
            float s = v_, s2 = v_ * v_;
#pragma unroll
            for (int off = 1; off < 64; off <<= 1) { s += __shfl_xor(s, off); s2 += __shfl_xor(s2, off); }
            float mu = s * (1.f / 64.f);
            float var = s2 * (1.f / 64.f) - mu * mu;
            float rs = rsqrtf(fmaxf(var, 0.f) + 1e-6f);
            xsm[r * 64 + c] = (v_ - mu) * rs * ws[I_FNS + c] + ws[I_FNB + c];
        }
        __syncthreads();
        {
            const float* W1 = ws + I_HW1;
            float a0 = ws[I_HB1 + c], a1 = ws[I_HB1 + c + 64];
#pragma unroll 8
            for (int k = 0; k < 64; ++k) {
                float x = xsm[r * 64 + k];
                a0 += x * W1[k * 128 + c];
                a1 += x * W1[k * 128 + c + 64];
            }
            hs[r * 128 + c] = fmaxf(a0, 0.f);
            hs[r * 128 + c + 64] = fmaxf(a1, 0.f);
        }
        __syncthreads();
        if (t < 8) {
            int rr = t >> 1, cb = t & 1;
            float a = ws[I_HB2 + cb];
            for (int k = 0; k < 128; ++k) a += hs[rr * 128 + k] * ws[I_HW2 + k * 2 + cb];
            float v = cb ? exp2f(a * 0.7213475204444817f) : a;   // exp(a/2)
            int rgg = r0 + rr;
            int idx = cb ? (N2 + rgg) : rgg;
            unsigned u0 = *(const unsigned*)ns_raw;
            if (u0 == 0x3F803F80u) ((bf16*)out_raw)[idx] = __float2bfloat16(v);
            else                   ((float*)out_raw)[idx] = v;
        }
    }
}

extern "C" void kernel_launch(void* const* d_in, const int* in_sizes, int n_in,
                              void* d_out, int out_size, void* d_ws, size_t ws_size,
                              hipStream_t stream) {
    float* ws = (float*)d_ws;

    InPtrs ptrs;
    for (int i = 0; i < 32; ++i) ptrs.p[i] = d_in[i];

    k_cvt<<<dim3(8, 32), 256, 0, stream>>>(ptrs, ws);
    k_pw<<<6, 256, 0, stream>>>(ws);
    k_embed<<<4096, 256, 0, stream>>>(ws);
    k_qkv<<<2048, 256, 0, stream>>>(0, ws);
    for (int i = 0; i < 6; ++i) {
        k_attn<<<dim3(64, 6, 4), 256, 0, stream>>>(i, ws);
        k_fuse<<<dim3(512, 2), 256, 0, stream>>>(i, ws, d_in[24], d_out);
    }
}